// Round 1
// 170.736 us; speedup vs baseline: 1.0012x; 1.0012x over previous
//
#include <hip/hip_runtime.h>
#include <math.h>

#define S_LEN 2048
#define E_DIM 512
#define NE (S_LEN * E_DIM)
#define H_NUM 8
#define WH 32
#define NOFF 65
#define PROW (H_NUM * NOFF) /* 520 */
#define PN (S_LEN * PROW)

typedef float f32x4 __attribute__((ext_vector_type(4)));
typedef short short8 __attribute__((ext_vector_type(8)));

__device__ __forceinline__ unsigned short f2bf(float f) {
    union { float f; unsigned u; } cv; cv.f = f;
    unsigned u = cv.u;
    u += 0x7fffu + ((u >> 16) & 1u);   // RNE
    return (unsigned short)(u >> 16);
}
__device__ __forceinline__ unsigned pk2(float x, float y) {
    return (unsigned)f2bf(x) | ((unsigned)f2bf(y) << 16);
}

// ---------------------------------------------------------------------------
// qkv (proven R3/R8): C = (x@W + bias)*scale, in-kernel bf16 cast, 64x64 tiles.
// ---------------------------------------------------------------------------
__device__ __forceinline__ void mfma_gemm_f32(
    const float* __restrict__ A, const float* __restrict__ W,
    const float* __restrict__ bias, float* __restrict__ C,
    float scale, int m0, int n0)
{
    __shared__ unsigned short As[64 * 40];
    __shared__ unsigned short Bs[64 * 40];
    const int tid = threadIdx.x;
    const int lane = tid & 63, wave = tid >> 6;
    const int quad = lane >> 4, l16 = lane & 15;
    const int wr = (wave >> 1) * 32, wc = (wave & 1) * 32;
    const int ar = tid >> 2, ac = (tid & 3) * 8;
    const int bn = tid & 63, bk0 = (tid >> 6) * 8;

    f32x4 acc00 = {0.f,0.f,0.f,0.f}, acc01 = acc00, acc10 = acc00, acc11 = acc00;

    for (int kk = 0; kk < E_DIM; kk += 32) {
        float4 a0 = *(const float4*)(A + (size_t)(m0 + ar) * E_DIM + kk + ac);
        float4 a1 = *(const float4*)(A + (size_t)(m0 + ar) * E_DIM + kk + ac + 4);
        float b[8];
#pragma unroll
        for (int j = 0; j < 8; ++j)
            b[j] = W[(size_t)(kk + bk0 + j) * E_DIM + n0 + bn];
        __syncthreads();
        uint4 ap; ap.x = pk2(a0.x, a0.y); ap.y = pk2(a0.z, a0.w);
        ap.z = pk2(a1.x, a1.y); ap.w = pk2(a1.z, a1.w);
        *(uint4*)(As + ar * 40 + ac) = ap;
        uint4 bp; bp.x = pk2(b[0], b[1]); bp.y = pk2(b[2], b[3]);
        bp.z = pk2(b[4], b[5]); bp.w = pk2(b[6], b[7]);
        *(uint4*)(Bs + bn * 40 + bk0) = bp;
        __syncthreads();
        short8 fa0 = *(const short8*)(As + (wr + l16) * 40 + quad * 8);
        short8 fa1 = *(const short8*)(As + (wr + 16 + l16) * 40 + quad * 8);
        short8 fb0 = *(const short8*)(Bs + (wc + l16) * 40 + quad * 8);
        short8 fb1 = *(const short8*)(Bs + (wc + 16 + l16) * 40 + quad * 8);
        acc00 = __builtin_amdgcn_mfma_f32_16x16x32_bf16(fa0, fb0, acc00, 0, 0, 0);
        acc01 = __builtin_amdgcn_mfma_f32_16x16x32_bf16(fa0, fb1, acc01, 0, 0, 0);
        acc10 = __builtin_amdgcn_mfma_f32_16x16x32_bf16(fa1, fb0, acc10, 0, 0, 0);
        acc11 = __builtin_amdgcn_mfma_f32_16x16x32_bf16(fa1, fb1, acc11, 0, 0, 0);
    }

#pragma unroll
    for (int mi = 0; mi < 2; ++mi) {
#pragma unroll
        for (int ni = 0; ni < 2; ++ni) {
            f32x4 a = (mi == 0) ? ((ni == 0) ? acc00 : acc01)
                                : ((ni == 0) ? acc10 : acc11);
            int n = n0 + wc + ni * 16 + l16;
            float bval = bias[n];
#pragma unroll
            for (int r = 0; r < 4; ++r) {
                int m = m0 + wr + mi * 16 + quad * 4 + r;
                C[(size_t)m * E_DIM + n] = (a[r] + bval) * scale;
            }
        }
    }
}

__global__ __launch_bounds__(256)
void qkv_gemm(const float* __restrict__ x,
              const float* __restrict__ Wq, const float* __restrict__ bq,
              const float* __restrict__ Wk, const float* __restrict__ bk,
              const float* __restrict__ Wv, const float* __restrict__ bv,
              float* __restrict__ q, float* __restrict__ k, float* __restrict__ v)
{
    const float* W; const float* b; float* o; float sc;
    if (blockIdx.z == 0)      { W = Wq; b = bq; o = q; sc = 0.125f; }
    else if (blockIdx.z == 1) { W = Wk; b = bk; o = k; sc = 1.0f; }
    else                      { W = Wv; b = bv; o = v; sc = 1.0f; }
    mfma_gemm_f32(x, W, b, o, sc, blockIdx.y * 64, blockIdx.x * 64);
}

// ---------------------------------------------------------------------------
// scores_d1 (proven R8): scores + edge-softmax + diffusion step 1, fused.
// ---------------------------------------------------------------------------
#define SDN 32
__global__ __launch_bounds__(256)
void scores_d1(const float* __restrict__ q, const float* __restrict__ k,
               const float* __restrict__ v, const float* __restrict__ amask,
               float* __restrict__ P, float* __restrict__ hA)
{
    const int i0 = blockIdx.x * SDN;
    const int h  = blockIdx.y;
    const int tid = threadIdx.x;
    __shared__ float ks[96 * 68];      // k rows [i0-32,i0+64); later v rows
    __shared__ float am[96];
    __shared__ float sc[SDN * 66];
    __shared__ float smx[SDN], sidn[SDN];
    __shared__ float ps[SDN * NOFF];

    for (int e = tid; e < 96 * 16; e += 256) {
        int lr = e >> 4, c4 = e & 15;
        int j = i0 - WH + lr;
        int jc = min(max(j, 0), S_LEN - 1);
        *(float4*)(ks + lr * 68 + c4 * 4) =
            *(const float4*)(k + (size_t)jc * E_DIM + h * 64 + c4 * 4);
    }
    if (tid < 96) {
        int j = i0 - WH + tid;
        am[tid] = (j >= 0 && j < S_LEN) ? amask[j] : -1.0f;
    }

    const int dst = tid >> 3;
    const int og  = tid & 7;
    float4 qreg[16];
    {
        const float4* qrow = (const float4*)(q + (size_t)(i0 + dst) * E_DIM + h * 64);
#pragma unroll
        for (int t = 0; t < 16; ++t) qreg[t] = qrow[t];
    }
    __syncthreads();

    for (int off = og; off < NOFF; off += 8) {
        int j = i0 + dst + off - WH;
        float s;
        if (j < 0 || j >= S_LEN) {
            s = -INFINITY;
        } else {
            int lr = dst + off;
            const float4* kr = (const float4*)(ks + lr * 68);
            float acc = 0.f;
#pragma unroll
            for (int t = 0; t < 16; ++t) {
                float4 a = qreg[t], bb = kr[t];
                acc += a.x * bb.x + a.y * bb.y + a.z * bb.z + a.w * bb.w;
            }
            s = (am[lr] >= 0.f) ? acc : -1e9f;
        }
        sc[dst * 66 + off] = s;
    }
    __syncthreads();   // sc done; ks no longer read as k

    for (int e = tid; e < 96 * 16; e += 256) {
        int lr = e >> 4, c4 = e & 15;
        int j = i0 - WH + lr;
        int jc = min(max(j, 0), S_LEN - 1);
        *(float4*)(ks + lr * 68 + c4 * 4) =
            *(const float4*)(v + (size_t)jc * E_DIM + h * 64 + c4 * 4);
    }
    if (tid < SDN) {
        float mx = -INFINITY;
        for (int o = 0; o < NOFF; ++o) mx = fmaxf(mx, sc[tid * 66 + o]);
        float dn = 0.f;
        for (int o = 0; o < NOFF; ++o) dn += expf(sc[tid * 66 + o] - mx);
        smx[tid] = mx; sidn[tid] = 1.f / dn;
    }
    __syncthreads();

    for (int e = tid; e < SDN * NOFF; e += 256) {
        int d = e / NOFF, off = e - d * NOFF;
        float pv = expf(sc[d * 66 + off] - smx[d]) * sidn[d];
        P[(size_t)(i0 + d) * PROW + h * NOFF + off] = pv;
        ps[e] = pv;
    }
    __syncthreads();

    {
        const int ci = tid & 15;
        const int ob = (tid >> 4) * 2;
        float4 a0 = {0,0,0,0}, a1 = a0;
        for (int lr = ob; lr < ob + 66; ++lr) {
            float4 hval = *(const float4*)(ks + lr * 68 + ci * 4);
            int o0 = lr - ob;
            if (o0 <= 64) {
                float p = ps[ob * NOFF + o0];
                a0.x += p * hval.x; a0.y += p * hval.y; a0.z += p * hval.z; a0.w += p * hval.w;
            }
            int o1 = o0 - 1;
            if ((unsigned)o1 <= 64u) {
                float p = ps[(ob + 1) * NOFF + o1];
                a1.x += p * hval.x; a1.y += p * hval.y; a1.z += p * hval.z; a1.w += p * hval.w;
            }
        }
#pragma unroll
        for (int r = 0; r < 2; ++r) {
            float4 a = r ? a1 : a0;
            float4 vv = *(const float4*)(ks + (WH + ob + r) * 68 + ci * 4);
            float4 o;
            o.x = 0.9f * a.x + 0.1f * vv.x;
            o.y = 0.9f * a.y + 0.1f * vv.y;
            o.z = 0.9f * a.z + 0.1f * vv.z;
            o.w = 0.9f * a.w + 0.1f * vv.w;
            *(float4*)(hA + (size_t)(i0 + ob + r) * E_DIM + h * 64 + ci * 4) = o;
        }
    }
}

// ---------------------------------------------------------------------------
// diffuse3m (proven R12): THREE diffusion steps via banded MFMA.
// block = 64 out rows x 64 cols (one head), 512 thr (8 waves). grid (32,8).
// ---------------------------------------------------------------------------
__global__ __launch_bounds__(512)
void diffuse3m(const float* __restrict__ hin, const float* __restrict__ v,
               const float* __restrict__ P, float* __restrict__ hout)
{
    __shared__ unsigned short inT[64 * 264];  // [col][in-row 0..255]; later m2T
    __shared__ unsigned short m1T[64 * 200];  // [col][mid1-row 0..191]
    __shared__ unsigned short ps[192 * 66];   // [row rk1][off 0..64] bf16
    unsigned short* m2T = inT;                // [col][mid2-row 0..127] stride 136
    const int i0 = blockIdx.x * 64;
    const int h  = blockIdx.y;
    const int c0 = h * 64;
    const int tid  = threadIdx.x;
    const int lane = tid & 63, wave = tid >> 6;
    const int quad = lane >> 4, l16 = lane & 15;

    for (int e = tid; e < 128 * 16; e += 512) {
        int rp = (e >> 4) * 2, c4 = (e & 15) * 4;
        int ja = min(max(i0 - 96 + rp,     0), S_LEN - 1);
        int jb = min(max(i0 - 96 + rp + 1, 0), S_LEN - 1);
        float4 ha = *(const float4*)(hin + (size_t)ja * E_DIM + c0 + c4);
        float4 hb = *(const float4*)(hin + (size_t)jb * E_DIM + c0 + c4);
        *(unsigned*)(inT + (c4 + 0) * 264 + rp) = pk2(ha.x, hb.x);
        *(unsigned*)(inT + (c4 + 1) * 264 + rp) = pk2(ha.y, hb.y);
        *(unsigned*)(inT + (c4 + 2) * 264 + rp) = pk2(ha.z, hb.z);
        *(unsigned*)(inT + (c4 + 3) * 264 + rp) = pk2(ha.w, hb.w);
    }
    for (int e = tid; e < 192 * 33; e += 512) {
        int mr = e / 33, t = e - mr * 33;
        int jc = min(max(i0 - 64 + mr, 0), S_LEN - 1);
        const float* pr = P + (size_t)jc * PROW + h * NOFF;
        if (t < 32)
            *(unsigned*)(ps + mr * 66 + t * 2) = pk2(pr[t * 2], pr[t * 2 + 1]);
        else
            ps[mr * 66 + 64] = f2bf(pr[64]);
    }
    __syncthreads();

    // ---- s1: mid1 rows (rk1 0..191). 24 units (12 m-tiles x 2 n-halves).
#pragma unroll
    for (int uu = 0; uu < 3; ++uu) {
        int u = wave + uu * 8;
        int mtb = (u >> 1) * 16;
        int ntb = (u & 1) * 32;
        f32x4 a0 = {0.f,0.f,0.f,0.f}, a1 = a0;
        int ks0 = mtb >> 5;
        const int m = mtb + l16;
#pragma unroll
        for (int t = 0; t < 3; ++t) {
            int k0q = (ks0 + t) * 32 + quad * 8;
            short8 fa;
#pragma unroll
            for (int j = 0; j < 8; ++j) {
                int idx = k0q + j - m;
                int idc = min(max(idx, 0), 64);
                unsigned short pv = ps[m * 66 + idc];
                fa[j] = ((unsigned)idx <= 64u) ? (short)pv : (short)0;
            }
            short8 fb0 = *(const short8*)(inT + (ntb + l16) * 264 + k0q);
            short8 fb1 = *(const short8*)(inT + (ntb + 16 + l16) * 264 + k0q);
            a0 = __builtin_amdgcn_mfma_f32_16x16x32_bf16(fa, fb0, a0, 0, 0, 0);
            a1 = __builtin_amdgcn_mfma_f32_16x16x32_bf16(fa, fb1, a1, 0, 0, 0);
        }
#pragma unroll
        for (int nt = 0; nt < 2; ++nt) {
            f32x4 a = nt ? a1 : a0;
            int n = ntb + nt * 16 + l16;
            float o[4];
#pragma unroll
            for (int r = 0; r < 4; ++r) {
                int gm = min(max(i0 - 64 + mtb + quad * 4 + r, 0), S_LEN - 1);
                o[r] = 0.9f * a[r] + 0.1f * v[(size_t)gm * E_DIM + c0 + n];
            }
            *(unsigned*)(m1T + n * 200 + mtb + quad * 4)     = pk2(o[0], o[1]);
            *(unsigned*)(m1T + n * 200 + mtb + quad * 4 + 2) = pk2(o[2], o[3]);
        }
    }
    __syncthreads();

    // ---- s2: mid2 rows (rk2 0..127), source m1T, P row rk2+32. 16 units.
    // Writes m2T which overlays inT (inT dead after s1).
#pragma unroll
    for (int uu = 0; uu < 2; ++uu) {
        int u = wave + uu * 8;
        int mtb = (u >> 1) * 16;
        int ntb = (u & 1) * 32;
        f32x4 a0 = {0.f,0.f,0.f,0.f}, a1 = a0;
        int ks0 = mtb >> 5;
        const int m = mtb + l16;
#pragma unroll
        for (int t = 0; t < 3; ++t) {
            int k0q = (ks0 + t) * 32 + quad * 8;
            short8 fa;
#pragma unroll
            for (int j = 0; j < 8; ++j) {
                int idx = k0q + j - m;
                int idc = min(max(idx, 0), 64);
                unsigned short pv = ps[(m + 32) * 66 + idc];
                fa[j] = ((unsigned)idx <= 64u) ? (short)pv : (short)0;
            }
            short8 fb0 = *(const short8*)(m1T + (ntb + l16) * 200 + k0q);
            short8 fb1 = *(const short8*)(m1T + (ntb + 16 + l16) * 200 + k0q);
            a0 = __builtin_amdgcn_mfma_f32_16x16x32_bf16(fa, fb0, a0, 0, 0, 0);
            a1 = __builtin_amdgcn_mfma_f32_16x16x32_bf16(fa, fb1, a1, 0, 0, 0);
        }
        __syncthreads();   // uniform across waves; orders m2T writes vs any
                           // straggling inT reads (defensive -- inT is dead)
#pragma unroll
        for (int nt = 0; nt < 2; ++nt) {
            f32x4 a = nt ? a1 : a0;
            int n = ntb + nt * 16 + l16;
            float o[4];
#pragma unroll
            for (int r = 0; r < 4; ++r) {
                int gm = min(max(i0 - 32 + mtb + quad * 4 + r, 0), S_LEN - 1);
                o[r] = 0.9f * a[r] + 0.1f * v[(size_t)gm * E_DIM + c0 + n];
            }
            *(unsigned*)(m2T + n * 136 + mtb + quad * 4)     = pk2(o[0], o[1]);
            *(unsigned*)(m2T + n * 136 + mtb + quad * 4 + 2) = pk2(o[2], o[3]);
        }
    }
    __syncthreads();

    // ---- s3: out rows (rk3 0..63), source m2T, P row rk3+64. 8 units.
    {
        int u = wave;
        int mtb = (u >> 1) * 16;
        int ntb = (u & 1) * 32;
        f32x4 a0 = {0.f,0.f,0.f,0.f}, a1 = a0;
        int ks0 = mtb >> 5;
        const int m = mtb + l16;
#pragma unroll
        for (int t = 0; t < 3; ++t) {
            int k0q = (ks0 + t) * 32 + quad * 8;
            short8 fa;
#pragma unroll
            for (int j = 0; j < 8; ++j) {
                int idx = k0q + j - m;
                int idc = min(max(idx, 0), 64);
                unsigned short pv = ps[(m + 64) * 66 + idc];
                fa[j] = ((unsigned)idx <= 64u) ? (short)pv : (short)0;
            }
            short8 fb0 = *(const short8*)(m2T + (ntb + l16) * 136 + k0q);
            short8 fb1 = *(const short8*)(m2T + (ntb + 16 + l16) * 136 + k0q);
            a0 = __builtin_amdgcn_mfma_f32_16x16x32_bf16(fa, fb0, a0, 0, 0, 0);
            a1 = __builtin_amdgcn_mfma_f32_16x16x32_bf16(fa, fb1, a1, 0, 0, 0);
        }
#pragma unroll
        for (int nt = 0; nt < 2; ++nt) {
            f32x4 a = nt ? a1 : a0;
            int n = ntb + nt * 16 + l16;
#pragma unroll
            for (int r = 0; r < 4; ++r) {
                int gm = i0 + mtb + quad * 4 + r;   // always in range
                size_t base = (size_t)gm * E_DIM + c0 + n;
                hout[base] = 0.9f * a[r] + 0.1f * v[base];
            }
        }
    }
}

// ---------------------------------------------------------------------------
// oln4 (NEW this round): diffusion step 5 hoisted to a PROLOGUE (all 8 waves,
// banded MFMA -> full 16x512 bf16 h5 tile in As16), then a double-buffered
// GEMM h5@Wo + bo + x + LayerNorm with ONE barrier per k-iteration.
// Replaces oln3 (42.5us, MfmaUtil 1%, 3 barriers/iter, band on 2/8 waves).
// Block = 16 rows x 512 cols, 512 thr, 128 blocks.
// LDS: As16 16.6KB + Bs dbuf 80KB (prologue h4T/ps16 alias Bs) ~= 100KB.
// ---------------------------------------------------------------------------
__global__ __launch_bounds__(512)
void oln4(const float* __restrict__ h4, const float* __restrict__ v,
          const float* __restrict__ P, const float* __restrict__ Wo,
          const float* __restrict__ bo, const float* __restrict__ x,
          const float* __restrict__ g, const float* __restrict__ lb,
          float* __restrict__ out)
{
    __shared__ unsigned short As16[16 * 520];   // h5 tile bf16; stride 520 (1040B,
                                                // slot coeff 65 odd -> even b128 spread)
    __shared__ unsigned short Bs2[2][512 * 40]; // Wo tile double buffer (proven layout)
    __shared__ float rsum[8][16], rsq[8][16];
    // prologue-only arrays alias the Bs region (Bs written only after prologue)
    unsigned short* h4T  = &Bs2[0][0];          // [256 local cols][96 krows] stride 104
    unsigned short* ps16 = &Bs2[0][0] + 26624;  // [16 m][head*65+off] stride 528

    const int tid = threadIdx.x;
    const int lane = tid & 63, wave = tid >> 6;
    const int quad = lane >> 4, l16 = lane & 15;
    const int m0 = blockIdx.x * 16;
    const int n = tid;

    // ---- stage P rows m0..m0+16 (all heads) once, bf16 (proven pattern)
    for (int e = tid; e < 16 * 260; e += 512) {
        int mr = e / 260, t = e - mr * 260;
        const float* pr = P + (size_t)(m0 + mr) * PROW;
        *(unsigned*)(ps16 + mr * 528 + t * 2) = pk2(pr[t * 2], pr[t * 2 + 1]);
    }

    // ---- prologue: h5[16][512] = 0.9*(P band @ h4) + 0.1*v, in two 256-col halves
    for (int hc = 0; hc < 2; ++hc) {
        // stage h4T [local col][krow 0..95] = bf16(h4[m0-32+krow][hc*256+col]).
        // lanes walk ROWS of one col-quad -> LDS writes 128B-contiguous per wave
        // (conflict-free); global float4 re-reads of each 64B line hit L1.
        for (int e = tid; e < 64 * 64; e += 512) {          // krows 0..63
            int r = e & 63, c4 = (e >> 6) * 4;
            int row = min(max(m0 - 32 + r, 0), S_LEN - 1);
            float4 hv = *(const float4*)(h4 + (size_t)row * E_DIM + hc * 256 + c4);
            h4T[(c4 + 0) * 104 + r] = f2bf(hv.x);
            h4T[(c4 + 1) * 104 + r] = f2bf(hv.y);
            h4T[(c4 + 2) * 104 + r] = f2bf(hv.z);
            h4T[(c4 + 3) * 104 + r] = f2bf(hv.w);
        }
        for (int e = tid; e < 32 * 64; e += 512) {          // krows 64..95
            int r = 64 + (e & 31), c4 = (e >> 5) * 4;
            int row = min(max(m0 - 32 + r, 0), S_LEN - 1);
            float4 hv = *(const float4*)(h4 + (size_t)row * E_DIM + hc * 256 + c4);
            h4T[(c4 + 0) * 104 + r] = f2bf(hv.x);
            h4T[(c4 + 1) * 104 + r] = f2bf(hv.y);
            h4T[(c4 + 2) * 104 + r] = f2bf(hv.z);
            h4T[(c4 + 3) * 104 + r] = f2bf(hv.w);
        }
        __syncthreads();   // h4T (and on hc==0: ps16) visible

        // band compute: wave owns cols [wave*32, +32) of this half.
        // Index algebra identical to proven R12 band build, hoisted.
        {
            const int hd = hc * 4 + (wave >> 1);   // head of this wave's col block
            short8 fa[3];
#pragma unroll
            for (int t = 0; t < 3; ++t) {
                int k0q = t * 32 + quad * 8;
#pragma unroll
                for (int j = 0; j < 8; ++j) {
                    int idx = k0q + j - l16;              // offset into P row (m=l16)
                    int idc = min(max(idx, 0), 64);
                    unsigned short pv = ps16[l16 * 528 + hd * NOFF + idc];
                    fa[t][j] = ((unsigned)idx <= 64u) ? (short)pv : (short)0;
                }
            }
#pragma unroll
            for (int nt = 0; nt < 2; ++nt) {
                int lc = wave * 32 + nt * 16;
                f32x4 ba = {0.f, 0.f, 0.f, 0.f};
#pragma unroll
                for (int t = 0; t < 3; ++t) {
                    short8 fb = *(const short8*)(h4T + (lc + l16) * 104 + t * 32 + quad * 8);
                    ba = __builtin_amdgcn_mfma_f32_16x16x32_bf16(fa[t], fb, ba, 0, 0, 0);
                }
                int gcol = hc * 256 + lc + l16;
#pragma unroll
                for (int r = 0; r < 4; ++r) {
                    int m = quad * 4 + r;
                    float vv = v[(size_t)(m0 + m) * E_DIM + gcol];
                    As16[m * 520 + gcol] = f2bf(0.9f * ba[r] + 0.1f * vv);
                }
            }
        }
        __syncthreads();   // band reads done (h4T reusable); As16 half visible
    }
    // After hc loop: As16 complete; h4T/ps16 dead -> Bs region free.

    // ---- main GEMM: y = h5 @ Wo, double-buffered Bs, 1 barrier / iter
    {
        float w0[32];
#pragma unroll
        for (int j = 0; j < 32; ++j)
            w0[j] = Wo[(size_t)j * E_DIM + n];
#pragma unroll
        for (int t = 0; t < 4; ++t) {
            uint4 bp;
            bp.x = pk2(w0[t*8+0], w0[t*8+1]); bp.y = pk2(w0[t*8+2], w0[t*8+3]);
            bp.z = pk2(w0[t*8+4], w0[t*8+5]); bp.w = pk2(w0[t*8+6], w0[t*8+7]);
            *(uint4*)(&Bs2[0][0] + n * 40 + t * 8) = bp;
        }
    }

    f32x4 acc[4];
#pragma unroll
    for (int t = 0; t < 4; ++t) acc[t] = (f32x4){0.f,0.f,0.f,0.f};

#pragma unroll 2
    for (int it = 0; it < 16; ++it) {
        float wn[32];
        if (it < 15) {
#pragma unroll
            for (int j = 0; j < 32; ++j)
                wn[j] = Wo[(size_t)((it + 1) * 32 + j) * E_DIM + n];   // issue early
        }
        __syncthreads();   // Bs2[it&1] ready; prev-iter reads drained

        short8 fa = *(const short8*)(As16 + l16 * 520 + it * 32 + quad * 8);
#pragma unroll
        for (int nt = 0; nt < 4; ++nt) {
            short8 fb = *(const short8*)(&Bs2[it & 1][0] +
                                         (wave * 64 + nt * 16 + l16) * 40 + quad * 8);
            acc[nt] = __builtin_amdgcn_mfma_f32_16x16x32_bf16(fa, fb, acc[nt], 0, 0, 0);
        }

        if (it < 15) {
#pragma unroll
            for (int t = 0; t < 4; ++t) {
                uint4 bp;
                bp.x = pk2(wn[t*8+0], wn[t*8+1]); bp.y = pk2(wn[t*8+2], wn[t*8+3]);
                bp.z = pk2(wn[t*8+4], wn[t*8+5]); bp.w = pk2(wn[t*8+6], wn[t*8+7]);
                *(uint4*)(&Bs2[(it + 1) & 1][0] + n * 40 + t * 8) = bp;
            }
        }
    }

    // ---- epilogue: bias + resid, LN (proven R4/R6/R8, verbatim)
    float s[4] = {0.f,0.f,0.f,0.f}, s2[4] = {0.f,0.f,0.f,0.f};
#pragma unroll
    for (int nt = 0; nt < 4; ++nt) {
        int nc = wave * 64 + nt * 16 + l16;
        float bv = bo[nc];
#pragma unroll
        for (int r = 0; r < 4; ++r) {
            int m = m0 + quad * 4 + r;
            float vl = acc[nt][r] + bv + x[(size_t)m * E_DIM + nc];
            acc[nt][r] = vl;
            s[r] += vl; s2[r] += vl * vl;
        }
    }
#pragma unroll
    for (int o = 1; o < 16; o <<= 1) {
#pragma unroll
        for (int r = 0; r < 4; ++r) {
            s[r]  += __shfl_xor(s[r], o, 64);
            s2[r] += __shfl_xor(s2[r], o, 64);
        }
    }
    if (l16 == 0) {
#pragma unroll
        for (int r = 0; r < 4; ++r) {
            rsum[wave][quad * 4 + r] = s[r];
            rsq[wave][quad * 4 + r]  = s2[r];
        }
    }
    __syncthreads();
    float mu[4], rs[4];
#pragma unroll
    for (int r = 0; r < 4; ++r) {
        int rl = quad * 4 + r;
        float tot = 0.f, tot2 = 0.f;
#pragma unroll
        for (int w = 0; w < 8; ++w) { tot += rsum[w][rl]; tot2 += rsq[w][rl]; }
        float m_ = tot * (1.f / 512.f);
        float var = tot2 * (1.f / 512.f) - m_ * m_;
        mu[r] = m_; rs[r] = rsqrtf(var + 1e-12f);
    }
#pragma unroll
    for (int nt = 0; nt < 4; ++nt) {
        int nc = wave * 64 + nt * 16 + l16;
        float gv = g[nc], bbv = lb[nc];
#pragma unroll
        for (int r = 0; r < 4; ++r) {
            int m = m0 + quad * 4 + r;
            out[(size_t)m * E_DIM + nc] = (acc[nt][r] - mu[r]) * rs[r] * gv + bbv;
        }
    }
}

// ---------------------------------------------------------------------------
extern "C" void kernel_launch(void* const* d_in, const int* in_sizes, int n_in,
                              void* d_out, int out_size, void* d_ws, size_t ws_size,
                              hipStream_t stream)
{
    const float* x     = (const float*)d_in[0];
    const float* amask = (const float*)d_in[1];
    const float* Wq = (const float*)d_in[4];
    const float* bq = (const float*)d_in[5];
    const float* Wk = (const float*)d_in[6];
    const float* bk = (const float*)d_in[7];
    const float* Wv = (const float*)d_in[8];
    const float* bv = (const float*)d_in[9];
    const float* Wo = (const float*)d_in[10];
    const float* bo = (const float*)d_in[11];
    const float* lng = (const float*)d_in[12];
    const float* lnb = (const float*)d_in[13];
    float* out = (float*)d_out;

    float* ws = (float*)d_ws;
    float* q  = ws;
    float* k  = ws + (size_t)NE;
    float* v  = ws + (size_t)2 * NE;
    float* P  = ws + (size_t)3 * NE;
    float* hA = ws + (size_t)3 * NE + PN;
    float* hB = hA + (size_t)NE;

    qkv_gemm<<<dim3(8, 32, 3), 256, 0, stream>>>(x, Wq, bq, Wk, bk, Wv, bv, q, k, v);

    scores_d1<<<dim3(64, 8), 256, 0, stream>>>(q, k, v, amask, P, hA);   // P + step 1

    diffuse3m<<<dim3(32, 8), 512, 0, stream>>>(hA, v, P, hB);            // steps 2-4

    oln4<<<128, 512, 0, stream>>>(hB, v, P, Wo, bo, x, lng, lnb, out);   // step 5 + GEMM + LN
}

// Round 2
// 165.347 us; speedup vs baseline: 1.0339x; 1.0326x over previous
//
#include <hip/hip_runtime.h>
#include <math.h>

#define S_LEN 2048
#define E_DIM 512
#define NE (S_LEN * E_DIM)
#define H_NUM 8
#define WH 32
#define NOFF 65
#define PROW (H_NUM * NOFF) /* 520 */
#define PN (S_LEN * PROW)

typedef float f32x4 __attribute__((ext_vector_type(4)));
typedef short short8 __attribute__((ext_vector_type(8)));

__device__ __forceinline__ unsigned short f2bf(float f) {
    union { float f; unsigned u; } cv; cv.f = f;
    unsigned u = cv.u;
    u += 0x7fffu + ((u >> 16) & 1u);   // RNE
    return (unsigned short)(u >> 16);
}
__device__ __forceinline__ unsigned pk2(float x, float y) {
    return (unsigned)f2bf(x) | ((unsigned)f2bf(y) << 16);
}

// Raw barrier: lgkmcnt(0) only (LDS visibility), NO vmcnt drain -- global
// loads stay in flight across the barrier (T3/T4 minimum form, m230/m201).
// Consuming code gets compiler dep-waitcnts automatically.
#define LGKM_BARRIER() do {                                   \
    __builtin_amdgcn_sched_barrier(0);                        \
    asm volatile("s_waitcnt lgkmcnt(0)" ::: "memory");        \
    __builtin_amdgcn_s_barrier();                             \
    __builtin_amdgcn_sched_barrier(0);                        \
} while (0)

// ---------------------------------------------------------------------------
// qkv (R2 rework): C = (x@W + bias)*scale, 64x64 tiles, double-buffered LDS,
// loads issued 2 iters ahead, ONE lgkm-only raw barrier per k-step (was 2
// full-drain __syncthreads). Math identical to proven R3/R8 version.
// ---------------------------------------------------------------------------
__device__ __forceinline__ void mfma_gemm_f32(
    const float* __restrict__ A, const float* __restrict__ W,
    const float* __restrict__ bias, float* __restrict__ C,
    float scale, int m0, int n0)
{
    __shared__ unsigned short As[2][64 * 40];
    __shared__ unsigned short Bs[2][64 * 40];
    const int tid = threadIdx.x;
    const int lane = tid & 63, wave = tid >> 6;
    const int quad = lane >> 4, l16 = lane & 15;
    const int wr = (wave >> 1) * 32, wc = (wave & 1) * 32;
    const int ar = tid >> 2, ac = (tid & 3) * 8;
    const int bn = tid & 63, bk0 = (tid >> 6) * 8;

    f32x4 acc00 = {0.f,0.f,0.f,0.f}, acc01 = acc00, acc10 = acc00, acc11 = acc00;

    const float* Arow = A + (size_t)(m0 + ar) * E_DIM;

    float4 a0r[2], a1r[2];
    float  br[2][8];

#define QLOAD(s_, i_) do {                                                    \
        int kk_ = (i_) * 32;                                                  \
        a0r[s_] = *(const float4*)(Arow + kk_ + ac);                          \
        a1r[s_] = *(const float4*)(Arow + kk_ + ac + 4);                      \
        _Pragma("unroll")                                                     \
        for (int j_ = 0; j_ < 8; ++j_)                                        \
            br[s_][j_] = W[(size_t)(kk_ + bk0 + j_) * E_DIM + n0 + bn];       \
    } while (0)

#define QPACK(s_, b_) do {                                                    \
        uint4 ap_;                                                            \
        ap_.x = pk2(a0r[s_].x, a0r[s_].y); ap_.y = pk2(a0r[s_].z, a0r[s_].w); \
        ap_.z = pk2(a1r[s_].x, a1r[s_].y); ap_.w = pk2(a1r[s_].z, a1r[s_].w); \
        *(uint4*)(&As[b_][0] + ar * 40 + ac) = ap_;                           \
        uint4 bp_;                                                            \
        bp_.x = pk2(br[s_][0], br[s_][1]); bp_.y = pk2(br[s_][2], br[s_][3]); \
        bp_.z = pk2(br[s_][4], br[s_][5]); bp_.w = pk2(br[s_][6], br[s_][7]); \
        *(uint4*)(&Bs[b_][0] + bn * 40 + bk0) = bp_;                          \
    } while (0)

    // prologue: stage step 0, issue step 1
    QLOAD(0, 0);
    QPACK(0, 0);
    QLOAD(1, 1);
    LGKM_BARRIER();

#pragma unroll
    for (int it = 0; it < 16; ++it) {
        if (it < 14) QLOAD(it & 1, it + 2);     // 2-ahead issue (stays in flight)

        const unsigned short* Ab = &As[it & 1][0];
        const unsigned short* Bb = &Bs[it & 1][0];
        short8 fa0 = *(const short8*)(Ab + (wr + l16) * 40 + quad * 8);
        short8 fa1 = *(const short8*)(Ab + (wr + 16 + l16) * 40 + quad * 8);
        short8 fb0 = *(const short8*)(Bb + (wc + l16) * 40 + quad * 8);
        short8 fb1 = *(const short8*)(Bb + (wc + 16 + l16) * 40 + quad * 8);
        acc00 = __builtin_amdgcn_mfma_f32_16x16x32_bf16(fa0, fb0, acc00, 0, 0, 0);
        acc01 = __builtin_amdgcn_mfma_f32_16x16x32_bf16(fa0, fb1, acc01, 0, 0, 0);
        acc10 = __builtin_amdgcn_mfma_f32_16x16x32_bf16(fa1, fb0, acc10, 0, 0, 0);
        acc11 = __builtin_amdgcn_mfma_f32_16x16x32_bf16(fa1, fb1, acc11, 0, 0, 0);

        if (it < 15) {
            QPACK((it + 1) & 1, (it + 1) & 1);  // pack next tile (dep-waitcnt here)
            LGKM_BARRIER();
        }
    }
#undef QLOAD
#undef QPACK

#pragma unroll
    for (int mi = 0; mi < 2; ++mi) {
#pragma unroll
        for (int ni = 0; ni < 2; ++ni) {
            f32x4 a = (mi == 0) ? ((ni == 0) ? acc00 : acc01)
                                : ((ni == 0) ? acc10 : acc11);
            int n = n0 + wc + ni * 16 + l16;
            float bval = bias[n];
#pragma unroll
            for (int r = 0; r < 4; ++r) {
                int m = m0 + wr + mi * 16 + quad * 4 + r;
                C[(size_t)m * E_DIM + n] = (a[r] + bval) * scale;
            }
        }
    }
}

__global__ __launch_bounds__(256)
void qkv_gemm(const float* __restrict__ x,
              const float* __restrict__ Wq, const float* __restrict__ bq,
              const float* __restrict__ Wk, const float* __restrict__ bk,
              const float* __restrict__ Wv, const float* __restrict__ bv,
              float* __restrict__ q, float* __restrict__ k, float* __restrict__ v)
{
    const float* W; const float* b; float* o; float sc;
    if (blockIdx.z == 0)      { W = Wq; b = bq; o = q; sc = 0.125f; }
    else if (blockIdx.z == 1) { W = Wk; b = bk; o = k; sc = 1.0f; }
    else                      { W = Wv; b = bv; o = v; sc = 1.0f; }
    mfma_gemm_f32(x, W, b, o, sc, blockIdx.y * 64, blockIdx.x * 64);
}

// ---------------------------------------------------------------------------
// scores_d1 (R2 rework): scores kept in the registers of the thread that
// computed them; softmax is an 8-lane __shfl_xor reduce (was: 32-thread
// serial loop with 224/256 lanes idle). sc/smx/sidn LDS arrays removed
// (43.5 -> 35 KB, 3 -> 4 blocks/CU). 3 barriers (was 4). Same math.
// ---------------------------------------------------------------------------
#define SDN 32
__global__ __launch_bounds__(256)
void scores_d1(const float* __restrict__ q, const float* __restrict__ k,
               const float* __restrict__ v, const float* __restrict__ amask,
               float* __restrict__ P, float* __restrict__ hA)
{
    const int i0 = blockIdx.x * SDN;
    const int h  = blockIdx.y;
    const int tid = threadIdx.x;
    __shared__ float ks[96 * 68];      // k rows [i0-32,i0+64); later v rows
    __shared__ float am[96];
    __shared__ float ps[SDN * NOFF];

    for (int e = tid; e < 96 * 16; e += 256) {
        int lr = e >> 4, c4 = e & 15;
        int j = i0 - WH + lr;
        int jc = min(max(j, 0), S_LEN - 1);
        *(float4*)(ks + lr * 68 + c4 * 4) =
            *(const float4*)(k + (size_t)jc * E_DIM + h * 64 + c4 * 4);
    }
    if (tid < 96) {
        int j = i0 - WH + tid;
        am[tid] = (j >= 0 && j < S_LEN) ? amask[j] : -1.0f;
    }

    const int dst = tid >> 3;          // 8 lanes per destination row
    const int og  = tid & 7;
    float4 qreg[16];
    {
        const float4* qrow = (const float4*)(q + (size_t)(i0 + dst) * E_DIM + h * 64);
#pragma unroll
        for (int t = 0; t < 16; ++t) qreg[t] = qrow[t];
    }
    __syncthreads();                   // B1: ks/am staged

    // scores for offsets og, og+8, ..., kept in regs
    float sreg[9];
#pragma unroll
    for (int t = 0; t < 9; ++t) sreg[t] = -INFINITY;
#pragma unroll
    for (int t = 0; t < 9; ++t) {
        int off = og + 8 * t;
        if (off > 64) break;
        int j = i0 + dst + off - WH;
        if (j >= 0 && j < S_LEN) {
            int lr = dst + off;
            const float4* kr = (const float4*)(ks + lr * 68);
            float acc = 0.f;
#pragma unroll
            for (int u = 0; u < 16; ++u) {
                float4 a = qreg[u], bb = kr[u];
                acc += a.x * bb.x + a.y * bb.y + a.z * bb.z + a.w * bb.w;
            }
            sreg[t] = (am[lr] >= 0.f) ? acc : -1e9f;
        }
    }
    __syncthreads();                   // B2: all k reads done; ks reusable

    // restage v into ks (global loads overlap the shuffle softmax below)
    for (int e = tid; e < 96 * 16; e += 256) {
        int lr = e >> 4, c4 = e & 15;
        int j = i0 - WH + lr;
        int jc = min(max(j, 0), S_LEN - 1);
        *(float4*)(ks + lr * 68 + c4 * 4) =
            *(const float4*)(v + (size_t)jc * E_DIM + h * 64 + c4 * 4);
    }

    // wave-parallel softmax within each 8-lane group (lanes share dst)
    float mx = sreg[0];
#pragma unroll
    for (int t = 1; t < 9; ++t) mx = fmaxf(mx, sreg[t]);
#pragma unroll
    for (int o = 1; o < 8; o <<= 1) mx = fmaxf(mx, __shfl_xor(mx, o, 64));
    float dn = 0.f;
#pragma unroll
    for (int t = 0; t < 9; ++t) {
        sreg[t] = expf(sreg[t] - mx);  // exp(-inf - finite) = 0 for dead slots
        dn += sreg[t];
    }
#pragma unroll
    for (int o = 1; o < 8; o <<= 1) dn += __shfl_xor(dn, o, 64);
    float rinv = 1.f / dn;
#pragma unroll
    for (int t = 0; t < 9; ++t) {
        int off = og + 8 * t;
        if (off > 64) break;
        float pv = sreg[t] * rinv;
        P[(size_t)(i0 + dst) * PROW + h * NOFF + off] = pv;
        ps[dst * NOFF + off] = pv;
    }
    __syncthreads();                   // B3: ps ready AND v staged

    {
        const int ci = tid & 15;
        const int ob = (tid >> 4) * 2;
        float4 a0 = {0,0,0,0}, a1 = a0;
        for (int lr = ob; lr < ob + 66; ++lr) {
            float4 hval = *(const float4*)(ks + lr * 68 + ci * 4);
            int o0 = lr - ob;
            if (o0 <= 64) {
                float p = ps[ob * NOFF + o0];
                a0.x += p * hval.x; a0.y += p * hval.y; a0.z += p * hval.z; a0.w += p * hval.w;
            }
            int o1 = o0 - 1;
            if ((unsigned)o1 <= 64u) {
                float p = ps[(ob + 1) * NOFF + o1];
                a1.x += p * hval.x; a1.y += p * hval.y; a1.z += p * hval.z; a1.w += p * hval.w;
            }
        }
#pragma unroll
        for (int r = 0; r < 2; ++r) {
            float4 a = r ? a1 : a0;
            float4 vv = *(const float4*)(ks + (WH + ob + r) * 68 + ci * 4);
            float4 o;
            o.x = 0.9f * a.x + 0.1f * vv.x;
            o.y = 0.9f * a.y + 0.1f * vv.y;
            o.z = 0.9f * a.z + 0.1f * vv.z;
            o.w = 0.9f * a.w + 0.1f * vv.w;
            *(float4*)(hA + (size_t)(i0 + ob + r) * E_DIM + h * 64 + ci * 4) = o;
        }
    }
}

// ---------------------------------------------------------------------------
// diffuse3m (proven R12, untouched): THREE diffusion steps via banded MFMA.
// block = 64 out rows x 64 cols (one head), 512 thr (8 waves). grid (32,8).
// ---------------------------------------------------------------------------
__global__ __launch_bounds__(512)
void diffuse3m(const float* __restrict__ hin, const float* __restrict__ v,
               const float* __restrict__ P, float* __restrict__ hout)
{
    __shared__ unsigned short inT[64 * 264];  // [col][in-row 0..255]; later m2T
    __shared__ unsigned short m1T[64 * 200];  // [col][mid1-row 0..191]
    __shared__ unsigned short ps[192 * 66];   // [row rk1][off 0..64] bf16
    unsigned short* m2T = inT;                // [col][mid2-row 0..127] stride 136
    const int i0 = blockIdx.x * 64;
    const int h  = blockIdx.y;
    const int c0 = h * 64;
    const int tid  = threadIdx.x;
    const int lane = tid & 63, wave = tid >> 6;
    const int quad = lane >> 4, l16 = lane & 15;

    for (int e = tid; e < 128 * 16; e += 512) {
        int rp = (e >> 4) * 2, c4 = (e & 15) * 4;
        int ja = min(max(i0 - 96 + rp,     0), S_LEN - 1);
        int jb = min(max(i0 - 96 + rp + 1, 0), S_LEN - 1);
        float4 ha = *(const float4*)(hin + (size_t)ja * E_DIM + c0 + c4);
        float4 hb = *(const float4*)(hin + (size_t)jb * E_DIM + c0 + c4);
        *(unsigned*)(inT + (c4 + 0) * 264 + rp) = pk2(ha.x, hb.x);
        *(unsigned*)(inT + (c4 + 1) * 264 + rp) = pk2(ha.y, hb.y);
        *(unsigned*)(inT + (c4 + 2) * 264 + rp) = pk2(ha.z, hb.z);
        *(unsigned*)(inT + (c4 + 3) * 264 + rp) = pk2(ha.w, hb.w);
    }
    for (int e = tid; e < 192 * 33; e += 512) {
        int mr = e / 33, t = e - mr * 33;
        int jc = min(max(i0 - 64 + mr, 0), S_LEN - 1);
        const float* pr = P + (size_t)jc * PROW + h * NOFF;
        if (t < 32)
            *(unsigned*)(ps + mr * 66 + t * 2) = pk2(pr[t * 2], pr[t * 2 + 1]);
        else
            ps[mr * 66 + 64] = f2bf(pr[64]);
    }
    __syncthreads();

    // ---- s1: mid1 rows (rk1 0..191). 24 units (12 m-tiles x 2 n-halves).
#pragma unroll
    for (int uu = 0; uu < 3; ++uu) {
        int u = wave + uu * 8;
        int mtb = (u >> 1) * 16;
        int ntb = (u & 1) * 32;
        f32x4 a0 = {0.f,0.f,0.f,0.f}, a1 = a0;
        int ks0 = mtb >> 5;
        const int m = mtb + l16;
#pragma unroll
        for (int t = 0; t < 3; ++t) {
            int k0q = (ks0 + t) * 32 + quad * 8;
            short8 fa;
#pragma unroll
            for (int j = 0; j < 8; ++j) {
                int idx = k0q + j - m;
                int idc = min(max(idx, 0), 64);
                unsigned short pv = ps[m * 66 + idc];
                fa[j] = ((unsigned)idx <= 64u) ? (short)pv : (short)0;
            }
            short8 fb0 = *(const short8*)(inT + (ntb + l16) * 264 + k0q);
            short8 fb1 = *(const short8*)(inT + (ntb + 16 + l16) * 264 + k0q);
            a0 = __builtin_amdgcn_mfma_f32_16x16x32_bf16(fa, fb0, a0, 0, 0, 0);
            a1 = __builtin_amdgcn_mfma_f32_16x16x32_bf16(fa, fb1, a1, 0, 0, 0);
        }
#pragma unroll
        for (int nt = 0; nt < 2; ++nt) {
            f32x4 a = nt ? a1 : a0;
            int n = ntb + nt * 16 + l16;
            float o[4];
#pragma unroll
            for (int r = 0; r < 4; ++r) {
                int gm = min(max(i0 - 64 + mtb + quad * 4 + r, 0), S_LEN - 1);
                o[r] = 0.9f * a[r] + 0.1f * v[(size_t)gm * E_DIM + c0 + n];
            }
            *(unsigned*)(m1T + n * 200 + mtb + quad * 4)     = pk2(o[0], o[1]);
            *(unsigned*)(m1T + n * 200 + mtb + quad * 4 + 2) = pk2(o[2], o[3]);
        }
    }
    __syncthreads();

    // ---- s2: mid2 rows (rk2 0..127), source m1T, P row rk2+32. 16 units.
#pragma unroll
    for (int uu = 0; uu < 2; ++uu) {
        int u = wave + uu * 8;
        int mtb = (u >> 1) * 16;
        int ntb = (u & 1) * 32;
        f32x4 a0 = {0.f,0.f,0.f,0.f}, a1 = a0;
        int ks0 = mtb >> 5;
        const int m = mtb + l16;
#pragma unroll
        for (int t = 0; t < 3; ++t) {
            int k0q = (ks0 + t) * 32 + quad * 8;
            short8 fa;
#pragma unroll
            for (int j = 0; j < 8; ++j) {
                int idx = k0q + j - m;
                int idc = min(max(idx, 0), 64);
                unsigned short pv = ps[(m + 32) * 66 + idc];
                fa[j] = ((unsigned)idx <= 64u) ? (short)pv : (short)0;
            }
            short8 fb0 = *(const short8*)(m1T + (ntb + l16) * 200 + k0q);
            short8 fb1 = *(const short8*)(m1T + (ntb + 16 + l16) * 200 + k0q);
            a0 = __builtin_amdgcn_mfma_f32_16x16x32_bf16(fa, fb0, a0, 0, 0, 0);
            a1 = __builtin_amdgcn_mfma_f32_16x16x32_bf16(fa, fb1, a1, 0, 0, 0);
        }
        __syncthreads();
#pragma unroll
        for (int nt = 0; nt < 2; ++nt) {
            f32x4 a = nt ? a1 : a0;
            int n = ntb + nt * 16 + l16;
            float o[4];
#pragma unroll
            for (int r = 0; r < 4; ++r) {
                int gm = min(max(i0 - 32 + mtb + quad * 4 + r, 0), S_LEN - 1);
                o[r] = 0.9f * a[r] + 0.1f * v[(size_t)gm * E_DIM + c0 + n];
            }
            *(unsigned*)(m2T + n * 136 + mtb + quad * 4)     = pk2(o[0], o[1]);
            *(unsigned*)(m2T + n * 136 + mtb + quad * 4 + 2) = pk2(o[2], o[3]);
        }
    }
    __syncthreads();

    // ---- s3: out rows (rk3 0..63), source m2T, P row rk3+64. 8 units.
    {
        int u = wave;
        int mtb = (u >> 1) * 16;
        int ntb = (u & 1) * 32;
        f32x4 a0 = {0.f,0.f,0.f,0.f}, a1 = a0;
        int ks0 = mtb >> 5;
        const int m = mtb + l16;
#pragma unroll
        for (int t = 0; t < 3; ++t) {
            int k0q = (ks0 + t) * 32 + quad * 8;
            short8 fa;
#pragma unroll
            for (int j = 0; j < 8; ++j) {
                int idx = k0q + j - m;
                int idc = min(max(idx, 0), 64);
                unsigned short pv = ps[(m + 64) * 66 + idc];
                fa[j] = ((unsigned)idx <= 64u) ? (short)pv : (short)0;
            }
            short8 fb0 = *(const short8*)(m2T + (ntb + l16) * 136 + k0q);
            short8 fb1 = *(const short8*)(m2T + (ntb + 16 + l16) * 136 + k0q);
            a0 = __builtin_amdgcn_mfma_f32_16x16x32_bf16(fa, fb0, a0, 0, 0, 0);
            a1 = __builtin_amdgcn_mfma_f32_16x16x32_bf16(fa, fb1, a1, 0, 0, 0);
        }
#pragma unroll
        for (int nt = 0; nt < 2; ++nt) {
            f32x4 a = nt ? a1 : a0;
            int n = ntb + nt * 16 + l16;
#pragma unroll
            for (int r = 0; r < 4; ++r) {
                int gm = i0 + mtb + quad * 4 + r;   // always in range
                size_t base = (size_t)gm * E_DIM + c0 + n;
                hout[base] = 0.9f * a[r] + 0.1f * v[base];
            }
        }
    }
}

// ---------------------------------------------------------------------------
// oln4 (R2 rework of main loop): prologue unchanged (step-5 band, all 8
// waves, -> As16). Main GEMM now uses raw lgkm-only barriers so the
// next-tile Wo loads are NOT drained at the barrier (previous version used
// __syncthreads whose vmcnt(0) drain defeated the prefetch).
// ---------------------------------------------------------------------------
__global__ __launch_bounds__(512)
void oln4(const float* __restrict__ h4, const float* __restrict__ v,
          const float* __restrict__ P, const float* __restrict__ Wo,
          const float* __restrict__ bo, const float* __restrict__ x,
          const float* __restrict__ g, const float* __restrict__ lb,
          float* __restrict__ out)
{
    __shared__ unsigned short As16[16 * 520];   // h5 tile bf16
    __shared__ unsigned short Bs2[2][512 * 40]; // Wo tile double buffer
    __shared__ float rsum[8][16], rsq[8][16];
    unsigned short* h4T  = &Bs2[0][0];          // prologue alias: [256 cols][96 rows] str 104
    unsigned short* ps16 = &Bs2[0][0] + 26624;  // prologue alias: [16 m][520] str 528

    const int tid = threadIdx.x;
    const int lane = tid & 63, wave = tid >> 6;
    const int quad = lane >> 4, l16 = lane & 15;
    const int m0 = blockIdx.x * 16;
    const int n = tid;

    for (int e = tid; e < 16 * 260; e += 512) {
        int mr = e / 260, t = e - mr * 260;
        const float* pr = P + (size_t)(m0 + mr) * PROW;
        *(unsigned*)(ps16 + mr * 528 + t * 2) = pk2(pr[t * 2], pr[t * 2 + 1]);
    }

    for (int hc = 0; hc < 2; ++hc) {
        for (int e = tid; e < 64 * 64; e += 512) {          // krows 0..63
            int r = e & 63, c4 = (e >> 6) * 4;
            int row = min(max(m0 - 32 + r, 0), S_LEN - 1);
            float4 hv = *(const float4*)(h4 + (size_t)row * E_DIM + hc * 256 + c4);
            h4T[(c4 + 0) * 104 + r] = f2bf(hv.x);
            h4T[(c4 + 1) * 104 + r] = f2bf(hv.y);
            h4T[(c4 + 2) * 104 + r] = f2bf(hv.z);
            h4T[(c4 + 3) * 104 + r] = f2bf(hv.w);
        }
        for (int e = tid; e < 32 * 64; e += 512) {          // krows 64..95
            int r = 64 + (e & 31), c4 = (e >> 5) * 4;
            int row = min(max(m0 - 32 + r, 0), S_LEN - 1);
            float4 hv = *(const float4*)(h4 + (size_t)row * E_DIM + hc * 256 + c4);
            h4T[(c4 + 0) * 104 + r] = f2bf(hv.x);
            h4T[(c4 + 1) * 104 + r] = f2bf(hv.y);
            h4T[(c4 + 2) * 104 + r] = f2bf(hv.z);
            h4T[(c4 + 3) * 104 + r] = f2bf(hv.w);
        }
        __syncthreads();

        {
            const int hd = hc * 4 + (wave >> 1);
            short8 fa[3];
#pragma unroll
            for (int t = 0; t < 3; ++t) {
                int k0q = t * 32 + quad * 8;
#pragma unroll
                for (int j = 0; j < 8; ++j) {
                    int idx = k0q + j - l16;
                    int idc = min(max(idx, 0), 64);
                    unsigned short pv = ps16[l16 * 528 + hd * NOFF + idc];
                    fa[t][j] = ((unsigned)idx <= 64u) ? (short)pv : (short)0;
                }
            }
#pragma unroll
            for (int nt = 0; nt < 2; ++nt) {
                int lc = wave * 32 + nt * 16;
                f32x4 ba = {0.f, 0.f, 0.f, 0.f};
#pragma unroll
                for (int t = 0; t < 3; ++t) {
                    short8 fb = *(const short8*)(h4T + (lc + l16) * 104 + t * 32 + quad * 8);
                    ba = __builtin_amdgcn_mfma_f32_16x16x32_bf16(fa[t], fb, ba, 0, 0, 0);
                }
                int gcol = hc * 256 + lc + l16;
#pragma unroll
                for (int r = 0; r < 4; ++r) {
                    int m = quad * 4 + r;
                    float vv = v[(size_t)(m0 + m) * E_DIM + gcol];
                    As16[m * 520 + gcol] = f2bf(0.9f * ba[r] + 0.1f * vv);
                }
            }
        }
        __syncthreads();
    }
    // h4T/ps16 dead -> Bs2 region free.

    // ---- main GEMM: y = h5 @ Wo, dbuf Bs2, raw lgkm-only barrier per iter
    {
        float w0[32];
#pragma unroll
        for (int j = 0; j < 32; ++j)
            w0[j] = Wo[(size_t)j * E_DIM + n];
#pragma unroll
        for (int t = 0; t < 4; ++t) {
            uint4 bp;
            bp.x = pk2(w0[t*8+0], w0[t*8+1]); bp.y = pk2(w0[t*8+2], w0[t*8+3]);
            bp.z = pk2(w0[t*8+4], w0[t*8+5]); bp.w = pk2(w0[t*8+6], w0[t*8+7]);
            *(uint4*)(&Bs2[0][0] + n * 40 + t * 8) = bp;
        }
    }
    LGKM_BARRIER();

    f32x4 acc[4];
#pragma unroll
    for (int t = 0; t < 4; ++t) acc[t] = (f32x4){0.f,0.f,0.f,0.f};

#pragma unroll
    for (int it = 0; it < 16; ++it) {
        float wn[32];
        if (it < 15) {
#pragma unroll
            for (int j = 0; j < 32; ++j)
                wn[j] = Wo[(size_t)((it + 1) * 32 + j) * E_DIM + n];  // stays in flight
        }

        short8 fa = *(const short8*)(As16 + l16 * 520 + it * 32 + quad * 8);
#pragma unroll
        for (int nt = 0; nt < 4; ++nt) {
            short8 fb = *(const short8*)(&Bs2[it & 1][0] +
                                         (wave * 64 + nt * 16 + l16) * 40 + quad * 8);
            acc[nt] = __builtin_amdgcn_mfma_f32_16x16x32_bf16(fa, fb, acc[nt], 0, 0, 0);
        }

        if (it < 15) {
#pragma unroll
            for (int t = 0; t < 4; ++t) {
                uint4 bp;
                bp.x = pk2(wn[t*8+0], wn[t*8+1]); bp.y = pk2(wn[t*8+2], wn[t*8+3]);
                bp.z = pk2(wn[t*8+4], wn[t*8+5]); bp.w = pk2(wn[t*8+6], wn[t*8+7]);
                *(uint4*)(&Bs2[(it + 1) & 1][0] + n * 40 + t * 8) = bp;
            }
            LGKM_BARRIER();
        }
    }

    // ---- epilogue: bias + resid, LN (proven R4/R6/R8, verbatim)
    float s[4] = {0.f,0.f,0.f,0.f}, s2[4] = {0.f,0.f,0.f,0.f};
#pragma unroll
    for (int nt = 0; nt < 4; ++nt) {
        int nc = wave * 64 + nt * 16 + l16;
        float bv = bo[nc];
#pragma unroll
        for (int r = 0; r < 4; ++r) {
            int m = m0 + quad * 4 + r;
            float vl = acc[nt][r] + bv + x[(size_t)m * E_DIM + nc];
            acc[nt][r] = vl;
            s[r] += vl; s2[r] += vl * vl;
        }
    }
#pragma unroll
    for (int o = 1; o < 16; o <<= 1) {
#pragma unroll
        for (int r = 0; r < 4; ++r) {
            s[r]  += __shfl_xor(s[r], o, 64);
            s2[r] += __shfl_xor(s2[r], o, 64);
        }
    }
    if (l16 == 0) {
#pragma unroll
        for (int r = 0; r < 4; ++r) {
            rsum[wave][quad * 4 + r] = s[r];
            rsq[wave][quad * 4 + r]  = s2[r];
        }
    }
    __syncthreads();
    float mu[4], rs[4];
#pragma unroll
    for (int r = 0; r < 4; ++r) {
        int rl = quad * 4 + r;
        float tot = 0.f, tot2 = 0.f;
#pragma unroll
        for (int w = 0; w < 8; ++w) { tot += rsum[w][rl]; tot2 += rsq[w][rl]; }
        float m_ = tot * (1.f / 512.f);
        float var = tot2 * (1.f / 512.f) - m_ * m_;
        mu[r] = m_; rs[r] = rsqrtf(var + 1e-12f);
    }
#pragma unroll
    for (int nt = 0; nt < 4; ++nt) {
        int nc = wave * 64 + nt * 16 + l16;
        float gv = g[nc], bbv = lb[nc];
#pragma unroll
        for (int r = 0; r < 4; ++r) {
            int m = m0 + quad * 4 + r;
            out[(size_t)m * E_DIM + nc] = (acc[nt][r] - mu[r]) * rs[r] * gv + bbv;
        }
    }
}

// ---------------------------------------------------------------------------
extern "C" void kernel_launch(void* const* d_in, const int* in_sizes, int n_in,
                              void* d_out, int out_size, void* d_ws, size_t ws_size,
                              hipStream_t stream)
{
    const float* x     = (const float*)d_in[0];
    const float* amask = (const float*)d_in[1];
    const float* Wq = (const float*)d_in[4];
    const float* bq = (const float*)d_in[5];
    const float* Wk = (const float*)d_in[6];
    const float* bk = (const float*)d_in[7];
    const float* Wv = (const float*)d_in[8];
    const float* bv = (const float*)d_in[9];
    const float* Wo = (const float*)d_in[10];
    const float* bo = (const float*)d_in[11];
    const float* lng = (const float*)d_in[12];
    const float* lnb = (const float*)d_in[13];
    float* out = (float*)d_out;

    float* ws = (float*)d_ws;
    float* q  = ws;
    float* k  = ws + (size_t)NE;
    float* v  = ws + (size_t)2 * NE;
    float* P  = ws + (size_t)3 * NE;
    float* hA = ws + (size_t)3 * NE + PN;
    float* hB = hA + (size_t)NE;

    qkv_gemm<<<dim3(8, 32, 3), 256, 0, stream>>>(x, Wq, bq, Wk, bk, Wv, bv, q, k, v);

    scores_d1<<<dim3(64, 8), 256, 0, stream>>>(q, k, v, amask, P, hA);   // P + step 1

    diffuse3m<<<dim3(32, 8), 512, 0, stream>>>(hA, v, P, hB);            // steps 2-4

    oln4<<<128, 512, 0, stream>>>(hB, v, P, Wo, bo, x, lng, lnb, out);   // step 5 + GEMM + LN
}

// Round 3
// 164.412 us; speedup vs baseline: 1.0397x; 1.0057x over previous
//
#include <hip/hip_runtime.h>
#include <math.h>

#define S_LEN 2048
#define E_DIM 512
#define NE (S_LEN * E_DIM)
#define H_NUM 8
#define WH 32
#define NOFF 65
#define PROW (H_NUM * NOFF) /* 520 */
#define PN (S_LEN * PROW)

typedef float f32x4 __attribute__((ext_vector_type(4)));
typedef short short8 __attribute__((ext_vector_type(8)));

__device__ __forceinline__ unsigned short f2bf(float f) {
    union { float f; unsigned u; } cv; cv.f = f;
    unsigned u = cv.u;
    u += 0x7fffu + ((u >> 16) & 1u);   // RNE
    return (unsigned short)(u >> 16);
}
__device__ __forceinline__ unsigned pk2(float x, float y) {
    return (unsigned)f2bf(x) | ((unsigned)f2bf(y) << 16);
}

// Raw barrier: lgkmcnt(0) only (LDS visibility), NO vmcnt drain -- global
// loads stay in flight across the barrier (T3/T4 minimum form).
#define LGKM_BARRIER() do {                                   \
    __builtin_amdgcn_sched_barrier(0);                        \
    asm volatile("s_waitcnt lgkmcnt(0)" ::: "memory");        \
    __builtin_amdgcn_s_barrier();                             \
    __builtin_amdgcn_sched_barrier(0);                        \
} while (0)

// ---------------------------------------------------------------------------
// qkv (proven R2-r2): C = (x@W + bias)*scale, 64x64 tiles, double-buffered
// LDS, loads 2 iters ahead, one lgkm-only barrier per k-step.
// ---------------------------------------------------------------------------
__device__ __forceinline__ void mfma_gemm_f32(
    const float* __restrict__ A, const float* __restrict__ W,
    const float* __restrict__ bias, float* __restrict__ C,
    float scale, int m0, int n0)
{
    __shared__ unsigned short As[2][64 * 40];
    __shared__ unsigned short Bs[2][64 * 40];
    const int tid = threadIdx.x;
    const int lane = tid & 63, wave = tid >> 6;
    const int quad = lane >> 4, l16 = lane & 15;
    const int wr = (wave >> 1) * 32, wc = (wave & 1) * 32;
    const int ar = tid >> 2, ac = (tid & 3) * 8;
    const int bn = tid & 63, bk0 = (tid >> 6) * 8;

    f32x4 acc00 = {0.f,0.f,0.f,0.f}, acc01 = acc00, acc10 = acc00, acc11 = acc00;

    const float* Arow = A + (size_t)(m0 + ar) * E_DIM;

    float4 a0r[2], a1r[2];
    float  br[2][8];

#define QLOAD(s_, i_) do {                                                    \
        int kk_ = (i_) * 32;                                                  \
        a0r[s_] = *(const float4*)(Arow + kk_ + ac);                          \
        a1r[s_] = *(const float4*)(Arow + kk_ + ac + 4);                      \
        _Pragma("unroll")                                                     \
        for (int j_ = 0; j_ < 8; ++j_)                                        \
            br[s_][j_] = W[(size_t)(kk_ + bk0 + j_) * E_DIM + n0 + bn];       \
    } while (0)

#define QPACK(s_, b_) do {                                                    \
        uint4 ap_;                                                            \
        ap_.x = pk2(a0r[s_].x, a0r[s_].y); ap_.y = pk2(a0r[s_].z, a0r[s_].w); \
        ap_.z = pk2(a1r[s_].x, a1r[s_].y); ap_.w = pk2(a1r[s_].z, a1r[s_].w); \
        *(uint4*)(&As[b_][0] + ar * 40 + ac) = ap_;                           \
        uint4 bp_;                                                            \
        bp_.x = pk2(br[s_][0], br[s_][1]); bp_.y = pk2(br[s_][2], br[s_][3]); \
        bp_.z = pk2(br[s_][4], br[s_][5]); bp_.w = pk2(br[s_][6], br[s_][7]); \
        *(uint4*)(&Bs[b_][0] + bn * 40 + bk0) = bp_;                          \
    } while (0)

    QLOAD(0, 0);
    QPACK(0, 0);
    QLOAD(1, 1);
    LGKM_BARRIER();

#pragma unroll
    for (int it = 0; it < 16; ++it) {
        if (it < 14) QLOAD(it & 1, it + 2);

        const unsigned short* Ab = &As[it & 1][0];
        const unsigned short* Bb = &Bs[it & 1][0];
        short8 fa0 = *(const short8*)(Ab + (wr + l16) * 40 + quad * 8);
        short8 fa1 = *(const short8*)(Ab + (wr + 16 + l16) * 40 + quad * 8);
        short8 fb0 = *(const short8*)(Bb + (wc + l16) * 40 + quad * 8);
        short8 fb1 = *(const short8*)(Bb + (wc + 16 + l16) * 40 + quad * 8);
        acc00 = __builtin_amdgcn_mfma_f32_16x16x32_bf16(fa0, fb0, acc00, 0, 0, 0);
        acc01 = __builtin_amdgcn_mfma_f32_16x16x32_bf16(fa0, fb1, acc01, 0, 0, 0);
        acc10 = __builtin_amdgcn_mfma_f32_16x16x32_bf16(fa1, fb0, acc10, 0, 0, 0);
        acc11 = __builtin_amdgcn_mfma_f32_16x16x32_bf16(fa1, fb1, acc11, 0, 0, 0);

        if (it < 15) {
            QPACK((it + 1) & 1, (it + 1) & 1);
            LGKM_BARRIER();
        }
    }
#undef QLOAD
#undef QPACK

#pragma unroll
    for (int mi = 0; mi < 2; ++mi) {
#pragma unroll
        for (int ni = 0; ni < 2; ++ni) {
            f32x4 a = (mi == 0) ? ((ni == 0) ? acc00 : acc01)
                                : ((ni == 0) ? acc10 : acc11);
            int n = n0 + wc + ni * 16 + l16;
            float bval = bias[n];
#pragma unroll
            for (int r = 0; r < 4; ++r) {
                int m = m0 + wr + mi * 16 + quad * 4 + r;
                C[(size_t)m * E_DIM + n] = (a[r] + bval) * scale;
            }
        }
    }
}

__global__ __launch_bounds__(256)
void qkv_gemm(const float* __restrict__ x,
              const float* __restrict__ Wq, const float* __restrict__ bq,
              const float* __restrict__ Wk, const float* __restrict__ bk,
              const float* __restrict__ Wv, const float* __restrict__ bv,
              float* __restrict__ q, float* __restrict__ k, float* __restrict__ v)
{
    const float* W; const float* b; float* o; float sc;
    if (blockIdx.z == 0)      { W = Wq; b = bq; o = q; sc = 0.125f; }
    else if (blockIdx.z == 1) { W = Wk; b = bk; o = k; sc = 1.0f; }
    else                      { W = Wv; b = bv; o = v; sc = 1.0f; }
    mfma_gemm_f32(x, W, b, o, sc, blockIdx.y * 64, blockIdx.x * 64);
}

// ---------------------------------------------------------------------------
// scores_d1 (proven R2-r2): scores in regs, 8-lane shuffle softmax,
// diffusion step 1 fused. Unchanged this round.
// ---------------------------------------------------------------------------
#define SDN 32
__global__ __launch_bounds__(256)
void scores_d1(const float* __restrict__ q, const float* __restrict__ k,
               const float* __restrict__ v, const float* __restrict__ amask,
               float* __restrict__ P, float* __restrict__ hA)
{
    const int i0 = blockIdx.x * SDN;
    const int h  = blockIdx.y;
    const int tid = threadIdx.x;
    __shared__ float ks[96 * 68];      // k rows [i0-32,i0+64); later v rows
    __shared__ float am[96];
    __shared__ float ps[SDN * NOFF];

    for (int e = tid; e < 96 * 16; e += 256) {
        int lr = e >> 4, c4 = e & 15;
        int j = i0 - WH + lr;
        int jc = min(max(j, 0), S_LEN - 1);
        *(float4*)(ks + lr * 68 + c4 * 4) =
            *(const float4*)(k + (size_t)jc * E_DIM + h * 64 + c4 * 4);
    }
    if (tid < 96) {
        int j = i0 - WH + tid;
        am[tid] = (j >= 0 && j < S_LEN) ? amask[j] : -1.0f;
    }

    const int dst = tid >> 3;
    const int og  = tid & 7;
    float4 qreg[16];
    {
        const float4* qrow = (const float4*)(q + (size_t)(i0 + dst) * E_DIM + h * 64);
#pragma unroll
        for (int t = 0; t < 16; ++t) qreg[t] = qrow[t];
    }
    __syncthreads();

    float sreg[9];
#pragma unroll
    for (int t = 0; t < 9; ++t) sreg[t] = -INFINITY;
#pragma unroll
    for (int t = 0; t < 9; ++t) {
        int off = og + 8 * t;
        if (off > 64) break;
        int j = i0 + dst + off - WH;
        if (j >= 0 && j < S_LEN) {
            int lr = dst + off;
            const float4* kr = (const float4*)(ks + lr * 68);
            float acc = 0.f;
#pragma unroll
            for (int u = 0; u < 16; ++u) {
                float4 a = qreg[u], bb = kr[u];
                acc += a.x * bb.x + a.y * bb.y + a.z * bb.z + a.w * bb.w;
            }
            sreg[t] = (am[lr] >= 0.f) ? acc : -1e9f;
        }
    }
    __syncthreads();

    for (int e = tid; e < 96 * 16; e += 256) {
        int lr = e >> 4, c4 = e & 15;
        int j = i0 - WH + lr;
        int jc = min(max(j, 0), S_LEN - 1);
        *(float4*)(ks + lr * 68 + c4 * 4) =
            *(const float4*)(v + (size_t)jc * E_DIM + h * 64 + c4 * 4);
    }

    float mx = sreg[0];
#pragma unroll
    for (int t = 1; t < 9; ++t) mx = fmaxf(mx, sreg[t]);
#pragma unroll
    for (int o = 1; o < 8; o <<= 1) mx = fmaxf(mx, __shfl_xor(mx, o, 64));
    float dn = 0.f;
#pragma unroll
    for (int t = 0; t < 9; ++t) {
        sreg[t] = expf(sreg[t] - mx);
        dn += sreg[t];
    }
#pragma unroll
    for (int o = 1; o < 8; o <<= 1) dn += __shfl_xor(dn, o, 64);
    float rinv = 1.f / dn;
#pragma unroll
    for (int t = 0; t < 9; ++t) {
        int off = og + 8 * t;
        if (off > 64) break;
        float pv = sreg[t] * rinv;
        P[(size_t)(i0 + dst) * PROW + h * NOFF + off] = pv;
        ps[dst * NOFF + off] = pv;
    }
    __syncthreads();

    {
        const int ci = tid & 15;
        const int ob = (tid >> 4) * 2;
        float4 a0 = {0,0,0,0}, a1 = a0;
        for (int lr = ob; lr < ob + 66; ++lr) {
            float4 hval = *(const float4*)(ks + lr * 68 + ci * 4);
            int o0 = lr - ob;
            if (o0 <= 64) {
                float p = ps[ob * NOFF + o0];
                a0.x += p * hval.x; a0.y += p * hval.y; a0.z += p * hval.z; a0.w += p * hval.w;
            }
            int o1 = o0 - 1;
            if ((unsigned)o1 <= 64u) {
                float p = ps[(ob + 1) * NOFF + o1];
                a1.x += p * hval.x; a1.y += p * hval.y; a1.z += p * hval.z; a1.w += p * hval.w;
            }
        }
#pragma unroll
        for (int r = 0; r < 2; ++r) {
            float4 a = r ? a1 : a0;
            float4 vv = *(const float4*)(ks + (WH + ob + r) * 68 + ci * 4);
            float4 o;
            o.x = 0.9f * a.x + 0.1f * vv.x;
            o.y = 0.9f * a.y + 0.1f * vv.y;
            o.z = 0.9f * a.z + 0.1f * vv.z;
            o.w = 0.9f * a.w + 0.1f * vv.w;
            *(float4*)(hA + (size_t)(i0 + ob + r) * E_DIM + h * 64 + ci * 4) = o;
        }
    }
}

// ---------------------------------------------------------------------------
// diffuse4m (NEW): FOUR diffusion steps (2,3,4,5) via banded MFMA, extending
// proven diffuse3m (same band algebra: step s uses ps[(m + 32*(s-1))] and
// input locals [m, m+64]). Output = h5 written DIRECTLY as bf16 (bit-identical
// to the bf16 cast oln4 performed). Removes oln's entire prologue.
// block = 64 out rows x 64 cols (one head), 512 thr (8 waves). grid (32,8).
// LDS: inT 64x328 (41.98K) + m1T 64x264 (33.79K) + ps 256x66 (33.79K) = 109.6K.
// Overlays: m2T(192,str200)->inT, m3T(128,str136)->m1T.
// ---------------------------------------------------------------------------
__global__ __launch_bounds__(512)
void diffuse4m(const float* __restrict__ hin, const float* __restrict__ v,
               const float* __restrict__ P, unsigned short* __restrict__ h5b)
{
    __shared__ unsigned short inT[64 * 328];  // h1: 320 rows [i0-128,i0+192)
    __shared__ unsigned short m1T[64 * 264];  // h2: 256 rows [i0-96,i0+160)
    __shared__ unsigned short ps[256 * 66];   // P rows [i0-96,i0+160) bf16
    unsigned short* m2T = inT;                // h3: 192 rows, stride 200
    unsigned short* m3T = m1T;                // h4: 128 rows, stride 136
    const int i0 = blockIdx.x * 64;
    const int h  = blockIdx.y;
    const int c0 = h * 64;
    const int tid  = threadIdx.x;
    const int lane = tid & 63, wave = tid >> 6;
    const int quad = lane >> 4, l16 = lane & 15;

    // stage h1 (320 rows) -> inT transposed bf16
    for (int e = tid; e < 160 * 16; e += 512) {
        int rp = (e >> 4) * 2, c4 = (e & 15) * 4;
        int ja = min(max(i0 - 128 + rp,     0), S_LEN - 1);
        int jb = min(max(i0 - 128 + rp + 1, 0), S_LEN - 1);
        float4 ha = *(const float4*)(hin + (size_t)ja * E_DIM + c0 + c4);
        float4 hb = *(const float4*)(hin + (size_t)jb * E_DIM + c0 + c4);
        *(unsigned*)(inT + (c4 + 0) * 328 + rp) = pk2(ha.x, hb.x);
        *(unsigned*)(inT + (c4 + 1) * 328 + rp) = pk2(ha.y, hb.y);
        *(unsigned*)(inT + (c4 + 2) * 328 + rp) = pk2(ha.z, hb.z);
        *(unsigned*)(inT + (c4 + 3) * 328 + rp) = pk2(ha.w, hb.w);
    }
    // stage P (256 rows) -> ps bf16
    for (int e = tid; e < 256 * 33; e += 512) {
        int mr = e / 33, t = e - mr * 33;
        int jc = min(max(i0 - 96 + mr, 0), S_LEN - 1);
        const float* pr = P + (size_t)jc * PROW + h * NOFF;
        if (t < 32)
            *(unsigned*)(ps + mr * 66 + t * 2) = pk2(pr[t * 2], pr[t * 2 + 1]);
        else
            ps[mr * 66 + 64] = f2bf(pr[64]);
    }
    __syncthreads();

    // ---- s1: h2 rows (0..255). 32 units (16 m-tiles x 2 n-halves).
#pragma unroll
    for (int uu = 0; uu < 4; ++uu) {
        int u = wave + uu * 8;
        int mtb = (u >> 1) * 16;
        int ntb = (u & 1) * 32;
        f32x4 a0 = {0.f,0.f,0.f,0.f}, a1 = a0;
        int ks0 = mtb >> 5;
        const int m = mtb + l16;
#pragma unroll
        for (int t = 0; t < 3; ++t) {
            int k0q = (ks0 + t) * 32 + quad * 8;
            short8 fa;
#pragma unroll
            for (int j = 0; j < 8; ++j) {
                int idx = k0q + j - m;
                int idc = min(max(idx, 0), 64);
                unsigned short pv = ps[m * 66 + idc];
                fa[j] = ((unsigned)idx <= 64u) ? (short)pv : (short)0;
            }
            short8 fb0 = *(const short8*)(inT + (ntb + l16) * 328 + k0q);
            short8 fb1 = *(const short8*)(inT + (ntb + 16 + l16) * 328 + k0q);
            a0 = __builtin_amdgcn_mfma_f32_16x16x32_bf16(fa, fb0, a0, 0, 0, 0);
            a1 = __builtin_amdgcn_mfma_f32_16x16x32_bf16(fa, fb1, a1, 0, 0, 0);
        }
#pragma unroll
        for (int nt = 0; nt < 2; ++nt) {
            f32x4 a = nt ? a1 : a0;
            int n = ntb + nt * 16 + l16;
            float o[4];
#pragma unroll
            for (int r = 0; r < 4; ++r) {
                int gm = min(max(i0 - 96 + mtb + quad * 4 + r, 0), S_LEN - 1);
                o[r] = 0.9f * a[r] + 0.1f * v[(size_t)gm * E_DIM + c0 + n];
            }
            *(unsigned*)(m1T + n * 264 + mtb + quad * 4)     = pk2(o[0], o[1]);
            *(unsigned*)(m1T + n * 264 + mtb + quad * 4 + 2) = pk2(o[2], o[3]);
        }
    }
    __syncthreads();   // inT reads done -> m2T overlay safe; m1T visible

    // ---- s2: h3 rows (0..191). 24 units. ps row m+32. m1T -> m2T.
#pragma unroll
    for (int uu = 0; uu < 3; ++uu) {
        int u = wave + uu * 8;
        int mtb = (u >> 1) * 16;
        int ntb = (u & 1) * 32;
        f32x4 a0 = {0.f,0.f,0.f,0.f}, a1 = a0;
        int ks0 = mtb >> 5;
        const int m = mtb + l16;
#pragma unroll
        for (int t = 0; t < 3; ++t) {
            int k0q = (ks0 + t) * 32 + quad * 8;
            short8 fa;
#pragma unroll
            for (int j = 0; j < 8; ++j) {
                int idx = k0q + j - m;
                int idc = min(max(idx, 0), 64);
                unsigned short pv = ps[(m + 32) * 66 + idc];
                fa[j] = ((unsigned)idx <= 64u) ? (short)pv : (short)0;
            }
            short8 fb0 = *(const short8*)(m1T + (ntb + l16) * 264 + k0q);
            short8 fb1 = *(const short8*)(m1T + (ntb + 16 + l16) * 264 + k0q);
            a0 = __builtin_amdgcn_mfma_f32_16x16x32_bf16(fa, fb0, a0, 0, 0, 0);
            a1 = __builtin_amdgcn_mfma_f32_16x16x32_bf16(fa, fb1, a1, 0, 0, 0);
        }
#pragma unroll
        for (int nt = 0; nt < 2; ++nt) {
            f32x4 a = nt ? a1 : a0;
            int n = ntb + nt * 16 + l16;
            float o[4];
#pragma unroll
            for (int r = 0; r < 4; ++r) {
                int gm = min(max(i0 - 64 + mtb + quad * 4 + r, 0), S_LEN - 1);
                o[r] = 0.9f * a[r] + 0.1f * v[(size_t)gm * E_DIM + c0 + n];
            }
            *(unsigned*)(m2T + n * 200 + mtb + quad * 4)     = pk2(o[0], o[1]);
            *(unsigned*)(m2T + n * 200 + mtb + quad * 4 + 2) = pk2(o[2], o[3]);
        }
    }
    __syncthreads();   // m1T reads done -> m3T overlay safe; m2T visible

    // ---- s3: h4 rows (0..127). 16 units. ps row m+64. m2T -> m3T.
#pragma unroll
    for (int uu = 0; uu < 2; ++uu) {
        int u = wave + uu * 8;
        int mtb = (u >> 1) * 16;
        int ntb = (u & 1) * 32;
        f32x4 a0 = {0.f,0.f,0.f,0.f}, a1 = a0;
        int ks0 = mtb >> 5;
        const int m = mtb + l16;
#pragma unroll
        for (int t = 0; t < 3; ++t) {
            int k0q = (ks0 + t) * 32 + quad * 8;
            short8 fa;
#pragma unroll
            for (int j = 0; j < 8; ++j) {
                int idx = k0q + j - m;
                int idc = min(max(idx, 0), 64);
                unsigned short pv = ps[(m + 64) * 66 + idc];
                fa[j] = ((unsigned)idx <= 64u) ? (short)pv : (short)0;
            }
            short8 fb0 = *(const short8*)(m2T + (ntb + l16) * 200 + k0q);
            short8 fb1 = *(const short8*)(m2T + (ntb + 16 + l16) * 200 + k0q);
            a0 = __builtin_amdgcn_mfma_f32_16x16x32_bf16(fa, fb0, a0, 0, 0, 0);
            a1 = __builtin_amdgcn_mfma_f32_16x16x32_bf16(fa, fb1, a1, 0, 0, 0);
        }
#pragma unroll
        for (int nt = 0; nt < 2; ++nt) {
            f32x4 a = nt ? a1 : a0;
            int n = ntb + nt * 16 + l16;
            float o[4];
#pragma unroll
            for (int r = 0; r < 4; ++r) {
                int gm = min(max(i0 - 32 + mtb + quad * 4 + r, 0), S_LEN - 1);
                o[r] = 0.9f * a[r] + 0.1f * v[(size_t)gm * E_DIM + c0 + n];
            }
            *(unsigned*)(m3T + n * 136 + mtb + quad * 4)     = pk2(o[0], o[1]);
            *(unsigned*)(m3T + n * 136 + mtb + quad * 4 + 2) = pk2(o[2], o[3]);
        }
    }
    __syncthreads();   // m2T reads done; m3T visible

    // ---- s4: h5 rows (0..63) -> global bf16. 8 units. ps row m+96.
    {
        int u = wave;
        int mtb = (u >> 1) * 16;
        int ntb = (u & 1) * 32;
        f32x4 a0 = {0.f,0.f,0.f,0.f}, a1 = a0;
        int ks0 = mtb >> 5;
        const int m = mtb + l16;
#pragma unroll
        for (int t = 0; t < 3; ++t) {
            int k0q = (ks0 + t) * 32 + quad * 8;
            short8 fa;
#pragma unroll
            for (int j = 0; j < 8; ++j) {
                int idx = k0q + j - m;
                int idc = min(max(idx, 0), 64);
                unsigned short pv = ps[(m + 96) * 66 + idc];
                fa[j] = ((unsigned)idx <= 64u) ? (short)pv : (short)0;
            }
            short8 fb0 = *(const short8*)(m3T + (ntb + l16) * 136 + k0q);
            short8 fb1 = *(const short8*)(m3T + (ntb + 16 + l16) * 136 + k0q);
            a0 = __builtin_amdgcn_mfma_f32_16x16x32_bf16(fa, fb0, a0, 0, 0, 0);
            a1 = __builtin_amdgcn_mfma_f32_16x16x32_bf16(fa, fb1, a1, 0, 0, 0);
        }
#pragma unroll
        for (int nt = 0; nt < 2; ++nt) {
            f32x4 a = nt ? a1 : a0;
            int n = ntb + nt * 16 + l16;
#pragma unroll
            for (int r = 0; r < 4; ++r) {
                int gm = i0 + mtb + quad * 4 + r;   // always in range
                float vv = v[(size_t)gm * E_DIM + c0 + n];
                h5b[(size_t)gm * E_DIM + c0 + n] = f2bf(0.9f * a[r] + 0.1f * vv);
            }
        }
    }
}

// ---------------------------------------------------------------------------
// oln5 (NEW): pure GEMM y = h5 @ Wo + bo + x + LayerNorm. NO prologue:
// A-fragments preloaded straight from global h5b (bf16) into 16 regs;
// Wo double-buffered with lgkm-only barriers (1/iter). 16 rows x 512 cols,
// 512 thr, grid 128. LDS = Bs dbuf 80K + 1K.
// ---------------------------------------------------------------------------
__global__ __launch_bounds__(512)
void oln5(const unsigned short* __restrict__ h5b, const float* __restrict__ Wo,
          const float* __restrict__ bo, const float* __restrict__ x,
          const float* __restrict__ g, const float* __restrict__ lb,
          float* __restrict__ out)
{
    __shared__ unsigned short Bs2[2][512 * 40];
    __shared__ float rsum[8][16], rsq[8][16];
    const int tid = threadIdx.x;
    const int lane = tid & 63, wave = tid >> 6;
    const int quad = lane >> 4, l16 = lane & 15;
    const int m0 = blockIdx.x * 16;
    const int n = tid;

    // preload ALL 16 A-fragments (row m0+l16 of h5, bf16) into registers
    short8 far_[16];
#pragma unroll
    for (int t = 0; t < 16; ++t)
        far_[t] = *(const short8*)(h5b + (size_t)(m0 + l16) * E_DIM + t * 32 + quad * 8);

    // stage Wo k-rows 0..31 into Bs2[0]
    {
        float w0[32];
#pragma unroll
        for (int j = 0; j < 32; ++j)
            w0[j] = Wo[(size_t)j * E_DIM + n];
#pragma unroll
        for (int t = 0; t < 4; ++t) {
            uint4 bp;
            bp.x = pk2(w0[t*8+0], w0[t*8+1]); bp.y = pk2(w0[t*8+2], w0[t*8+3]);
            bp.z = pk2(w0[t*8+4], w0[t*8+5]); bp.w = pk2(w0[t*8+6], w0[t*8+7]);
            *(uint4*)(&Bs2[0][0] + n * 40 + t * 8) = bp;
        }
    }
    LGKM_BARRIER();

    f32x4 acc[4];
#pragma unroll
    for (int t = 0; t < 4; ++t) acc[t] = (f32x4){0.f,0.f,0.f,0.f};

#pragma unroll
    for (int it = 0; it < 16; ++it) {
        float wn[32];
        if (it < 15) {
#pragma unroll
            for (int j = 0; j < 32; ++j)
                wn[j] = Wo[(size_t)((it + 1) * 32 + j) * E_DIM + n];  // in flight
        }

#pragma unroll
        for (int nt = 0; nt < 4; ++nt) {
            short8 fb = *(const short8*)(&Bs2[it & 1][0] +
                                         (wave * 64 + nt * 16 + l16) * 40 + quad * 8);
            acc[nt] = __builtin_amdgcn_mfma_f32_16x16x32_bf16(far_[it], fb, acc[nt], 0, 0, 0);
        }

        if (it < 15) {
#pragma unroll
            for (int t = 0; t < 4; ++t) {
                uint4 bp;
                bp.x = pk2(wn[t*8+0], wn[t*8+1]); bp.y = pk2(wn[t*8+2], wn[t*8+3]);
                bp.z = pk2(wn[t*8+4], wn[t*8+5]); bp.w = pk2(wn[t*8+6], wn[t*8+7]);
                *(uint4*)(&Bs2[(it + 1) & 1][0] + n * 40 + t * 8) = bp;
            }
            LGKM_BARRIER();
        }
    }

    // ---- epilogue: bias + resid, LN (proven, verbatim)
    float s[4] = {0.f,0.f,0.f,0.f}, s2[4] = {0.f,0.f,0.f,0.f};
#pragma unroll
    for (int nt = 0; nt < 4; ++nt) {
        int nc = wave * 64 + nt * 16 + l16;
        float bv = bo[nc];
#pragma unroll
        for (int r = 0; r < 4; ++r) {
            int m = m0 + quad * 4 + r;
            float vl = acc[nt][r] + bv + x[(size_t)m * E_DIM + nc];
            acc[nt][r] = vl;
            s[r] += vl; s2[r] += vl * vl;
        }
    }
#pragma unroll
    for (int o = 1; o < 16; o <<= 1) {
#pragma unroll
        for (int r = 0; r < 4; ++r) {
            s[r]  += __shfl_xor(s[r], o, 64);
            s2[r] += __shfl_xor(s2[r], o, 64);
        }
    }
    if (l16 == 0) {
#pragma unroll
        for (int r = 0; r < 4; ++r) {
            rsum[wave][quad * 4 + r] = s[r];
            rsq[wave][quad * 4 + r]  = s2[r];
        }
    }
    __syncthreads();
    float mu[4], rs[4];
#pragma unroll
    for (int r = 0; r < 4; ++r) {
        int rl = quad * 4 + r;
        float tot = 0.f, tot2 = 0.f;
#pragma unroll
        for (int w = 0; w < 8; ++w) { tot += rsum[w][rl]; tot2 += rsq[w][rl]; }
        float m_ = tot * (1.f / 512.f);
        float var = tot2 * (1.f / 512.f) - m_ * m_;
        mu[r] = m_; rs[r] = rsqrtf(var + 1e-12f);
    }
#pragma unroll
    for (int nt = 0; nt < 4; ++nt) {
        int nc = wave * 64 + nt * 16 + l16;
        float gv = g[nc], bbv = lb[nc];
#pragma unroll
        for (int r = 0; r < 4; ++r) {
            int m = m0 + quad * 4 + r;
            out[(size_t)m * E_DIM + nc] = (acc[nt][r] - mu[r]) * rs[r] * gv + bbv;
        }
    }
}

// ---------------------------------------------------------------------------
extern "C" void kernel_launch(void* const* d_in, const int* in_sizes, int n_in,
                              void* d_out, int out_size, void* d_ws, size_t ws_size,
                              hipStream_t stream)
{
    const float* x     = (const float*)d_in[0];
    const float* amask = (const float*)d_in[1];
    const float* Wq = (const float*)d_in[4];
    const float* bq = (const float*)d_in[5];
    const float* Wk = (const float*)d_in[6];
    const float* bk = (const float*)d_in[7];
    const float* Wv = (const float*)d_in[8];
    const float* bv = (const float*)d_in[9];
    const float* Wo = (const float*)d_in[10];
    const float* bo = (const float*)d_in[11];
    const float* lng = (const float*)d_in[12];
    const float* lnb = (const float*)d_in[13];
    float* out = (float*)d_out;

    float* ws = (float*)d_ws;
    float* q  = ws;
    float* k  = ws + (size_t)NE;
    float* v  = ws + (size_t)2 * NE;
    float* P  = ws + (size_t)3 * NE;
    float* hA = ws + (size_t)3 * NE + PN;
    unsigned short* h5b = (unsigned short*)(ws + (size_t)4 * NE + PN);  // NE bf16

    qkv_gemm<<<dim3(8, 32, 3), 256, 0, stream>>>(x, Wq, bq, Wk, bk, Wv, bv, q, k, v);

    scores_d1<<<dim3(64, 8), 256, 0, stream>>>(q, k, v, amask, P, hA);   // P + step 1

    diffuse4m<<<dim3(32, 8), 512, 0, stream>>>(hA, v, P, h5b);           // steps 2-5

    oln5<<<128, 512, 0, stream>>>(h5b, Wo, bo, x, lng, lnb, out);        // GEMM + LN
}